// Round 10
// baseline (344.830 us; speedup 1.0000x reference)
//
#include <hip/hip_runtime.h>
#include <hip/hip_bf16.h>
#include <stdint.h>

// VQ nearest-codebook: B=8,N=4096,C=256,K=8192
// R18 = B LDS path DELETED. With per-wave private B (R14+) there is zero
// cross-wave reuse, so global->LDS->reg was a pure round-trip tax: the MFMA
// B-fragment is 16 contiguous bytes of cbhi per lane (row=c0+nf*16+l15,
// byte ks*64+quad*16; 64B-granule coalesced gather, L2-resident 4MB).
// Now: B fragments load directly global->VGPR, ping-pong b[2][4] (32 regs),
// t+1 loads issued before t's MFMAs; compiler emits the counted vmcnt
// before each consuming MFMA (m97: fine-grained waits). Removes per step:
// 4 gl16 + 4 ds_read_b128 + lgkm waits + ALL B bank conflicts (8.4M -> ~0
// expected - the signature). LDS = 64KB A only. A staging/read, epilogue
// (med3 top-2, butterfly, records), finalize: identical to verified R17.

#define M_ROWS 32768   // B*N
#define KCODES 8192
#define CDIM   256
#define BM 128         // rows per block
#define BNT 256        // codes per tile
#define BK 32
#define NTILES 32      // KCODES / BNT
#define NREC 32        // records per row (each = top-2 over a 256-code subset)
#define MARGIN 0.75f   // >> hi-GEMM err (~0.32) + 2x key quantization (0.125)

typedef _Float16 f16x8 __attribute__((ext_vector_type(8)));
typedef _Float16 f16x4 __attribute__((ext_vector_type(4)));
typedef float    f32x4 __attribute__((ext_vector_type(4)));

#define WAITV(N) asm volatile("s_waitcnt vmcnt(" #N ")" ::: "memory")
#define CPIN()   asm volatile("" ::: "memory")

__device__ __forceinline__ unsigned umin2(unsigned a, unsigned b) { return a < b ? a : b; }
__device__ __forceinline__ unsigned umed3(unsigned a, unsigned b, unsigned c) {
  unsigned d;
  asm("v_med3_u32 %0, %1, %2, %3" : "=v"(d) : "v"(a), "v"(b), "v"(c));
  return d;
}

// ---------------- prep: fp16 hi (scaled by 64) + row sq-norms ----------------
__global__ void vq_prep(const float* __restrict__ x, const float* __restrict__ cb,
                        _Float16* __restrict__ xhi, _Float16* __restrict__ cbhi,
                        float* __restrict__ xsq, float* __restrict__ cbsq) {
  const int wave = threadIdx.x >> 6, lane = threadIdx.x & 63;
  const int row = blockIdx.x * 4 + wave;     // one wave per row
  const float* src;
  _Float16* dhi;
  float* dsq;
  if (row < M_ROWS) {
    src = x + (size_t)row * CDIM;  dhi = xhi + (size_t)row * CDIM;  dsq = xsq + row;
  } else {
    const int r = row - M_ROWS;
    src = cb + (size_t)r * CDIM;   dhi = cbhi + (size_t)r * CDIM;   dsq = cbsq + r;
  }
  const float4 v = *(const float4*)(src + lane * 4);
  f16x4 h;
  h[0] = (_Float16)(v.x * 64.0f); h[1] = (_Float16)(v.y * 64.0f);
  h[2] = (_Float16)(v.z * 64.0f); h[3] = (_Float16)(v.w * 64.0f);
  *(f16x4*)(dhi + lane * 4) = h;
  float s = v.x * v.x + v.y * v.y + v.z * v.z + v.w * v.w;
  #pragma unroll
  for (int off = 32; off > 0; off >>= 1) s += __shfl_down(s, off, 64);
  if (lane == 0) *dsq = s;
}

// ---------------- pass1: A-in-LDS, B-direct-to-reg GEMM + top-2 records ----------------
__device__ __forceinline__ void gl16p(const void* g, void* l) {
  __builtin_amdgcn_global_load_lds(
      (const __attribute__((address_space(1))) unsigned int*)g,
      (__attribute__((address_space(3))) unsigned int*)l, 16, 0, 0);
}

__global__ __launch_bounds__(512) void vq_pass1(
    const _Float16* __restrict__ xhi, const _Float16* __restrict__ cbhi,
    const float* __restrict__ cbsqg, uint2* __restrict__ srec) {
  extern __shared__ char smem[];
  _Float16* sA = (_Float16*)smem;             // 128 x 256 fp16 = 64 KB (shared, RO)

  const int tid  = threadIdx.x;
  const int wave = tid >> 6, lane = tid & 63;
  const int quad = lane >> 4, l15 = lane & 15;
  const int mbase = blockIdx.x * BM;
  const int wrow = (wave >> 2) * 64;    // row half
  const int q    = wave & 3;            // col quarter
  const int wcol = q * 64;

  // ---- stage A once (8 gl16/wave); certified before the barrier below.
  {
    const int ar = lane >> 5;            // row within pair
    const int as = lane & 31;            // 16B slot
    #pragma unroll
    for (int t = 0; t < 8; ++t) {
      const int rb  = (wave * 8 + t) * 2;
      const int row = rb + ar;
      const int slot = as ^ (row & 7);
      gl16p(xhi + (size_t)(mbase + row) * CDIM + slot * 8, sA + rb * CDIM);
    }
  }
  CPIN();   // pin A gl16s oldest in the vmcnt FIFO

  const int fcolxor = (l15 >> 1) & 3;   // unused marker (kept geometry notes)
  (void)fcolxor;
  const int asw = l15 & 7;              // A frag de-swizzle

  // ---- B fragment byte offsets into cbhi (per-lane, 32-bit):
  // frag(nf) for (nt,ks): (nt*256 + wcol + nf*16 + l15)*512 + ks*64 + quad*16
  const char* cbB = (const char*)cbhi;
  unsigned bo[4];
  #pragma unroll
  for (int nf = 0; nf < 4; ++nf)
    bo[nf] = (unsigned)((wcol + nf * 16 + l15) * 512 + quad * 16);

  // ping-pong B register buffers (4 frags x 4 VGPR x 2 = 32 regs)
  f16x8 b[2][4];
  // prologue: load B(nt0,ks0) into b[0]; cq_cur; then certify A, barrier.
  #pragma unroll
  for (int nf = 0; nf < 4; ++nf)
    b[0][nf] = *(const f16x8*)(cbB + bo[nf]);
  float cq_cur[4], cq_nxt[4];
  #pragma unroll
  for (int j = 0; j < 4; ++j) cq_cur[j] = cbsqg[wcol + j * 16 + l15];
  CPIN();
  WAITV(8);                       // retire A(8); leave b0(4)+cq(4) in flight
  __builtin_amdgcn_s_barrier();   // the only barrier
  CPIN();

  // precomputed A read base
  const char* sArow = (const char*)sA + (wrow + l15) * 512;  // + aoff + mf*8192

  unsigned k1[4][4], k2[4][4];

  for (int nt = 0; nt < NTILES; ++nt) {
    const bool lastnt = (nt == NTILES - 1);
    if ((nt & 3) == 0) {   // open subchunk (4 nt x 64 cols = 256 codes / record)
      #pragma unroll
      for (int mf = 0; mf < 4; ++mf)
        #pragma unroll
        for (int i = 0; i < 4; ++i) { k1[mf][i] = 0x7fffffffu; k2[mf][i] = 0x7fffffffu; }
    }

    f32x4 acc[4][4];
    #pragma unroll
    for (int mf = 0; mf < 4; ++mf)
      #pragma unroll
      for (int nf = 0; nf < 4; ++nf) {
        f32x4 z = {0.0f, 0.0f, 0.0f, 0.0f};
        acc[mf][nf] = z;
      }

    #pragma unroll
    for (int ks = 0; ks < 8; ++ks) {
      // ---- issue B(t+1) into the other buffer (compiler tracks and emits
      // the counted vmcnt before the consuming MFMAs; never a full drain).
      if (ks < 7) {
        #pragma unroll
        for (int nf = 0; nf < 4; ++nf)
          b[(ks + 1) & 1][nf] = *(const f16x8*)(cbB + bo[nf] + (ks + 1) * 64);
      } else if (!lastnt) {
        #pragma unroll
        for (int nf = 0; nf < 4; ++nf) bo[nf] += 131072u;   // next 256-code tile
        #pragma unroll
        for (int nf = 0; nf < 4; ++nf)
          b[0][nf] = *(const f16x8*)(cbB + bo[nf]);
        #pragma unroll
        for (int j = 0; j < 4; ++j)
          cq_nxt[j] = cbsqg[(nt + 1) * BNT + wcol + j * 16 + l15];
      }

      // ---- A frags from LDS, then MFMA with b[ks&1]
      const int aoff = (((ks * 4 + quad) ^ asw) << 4);
      const char* ab = sArow + aoff;
      const f16x8 ah0 = *(const f16x8*)(ab);
      const f16x8 ah1 = *(const f16x8*)(ab + 8192);
      const f16x8 ah2 = *(const f16x8*)(ab + 16384);
      const f16x8 ah3 = *(const f16x8*)(ab + 24576);
      __builtin_amdgcn_s_setprio(1);
      #pragma unroll
      for (int nf = 0; nf < 4; ++nf) {
        const f16x8 bh = b[ks & 1][nf];
        acc[0][nf] = __builtin_amdgcn_mfma_f32_16x16x32_f16(ah0, bh, acc[0][nf], 0, 0, 0);
        acc[1][nf] = __builtin_amdgcn_mfma_f32_16x16x32_f16(ah1, bh, acc[1][nf], 0, 0, 0);
        acc[2][nf] = __builtin_amdgcn_mfma_f32_16x16x32_f16(ah2, bh, acc[2][nf], 0, 0, 0);
        acc[3][nf] = __builtin_amdgcn_mfma_f32_16x16x32_f16(ah3, bh, acc[3][nf], 0, 0, 0);
      }
      __builtin_amdgcn_s_setprio(0);
    }

    // int-key top-2 insert: key = (uint)(16*v + 32768) << 13 | col
    // v = cbsq - 2*dot; acc = 4096*dot => 16*v = (16*cbsq+32768) - acc/128
    // k2' = med3(k1,k2,key) == min(k2, max(k1,key)) given k1<=k2 invariant.
    #pragma unroll
    for (int nf = 0; nf < 4; ++nf) {
      const int col = nt * BNT + wcol + nf * 16 + l15;   // global code (C/D: col = lane&15)
      const float cq16 = fmaf(cq_cur[nf], 16.0f, 32768.0f);
      #pragma unroll
      for (int mf = 0; mf < 4; ++mf)
        #pragma unroll
        for (int i = 0; i < 4; ++i) {
          const float kf = fmaf(acc[mf][nf][i], -0.0078125f, cq16);
          const unsigned key = ((unsigned)kf << 13) | (unsigned)col;
          k2[mf][i] = umed3(k1[mf][i], k2[mf][i], key);
          k1[mf][i] = umin2(k1[mf][i], key);
        }
    }

    if ((nt & 3) == 3) {   // close subchunk: 16-lane top-2 butterfly merge, store record
      const int g = (nt >> 2) * 4 + q;              // 0..31
      #pragma unroll
      for (int mf = 0; mf < 4; ++mf)
        #pragma unroll
        for (int i = 0; i < 4; ++i) {
          unsigned a1 = k1[mf][i], a2 = k2[mf][i];
          #pragma unroll
          for (int m = 1; m <= 8; m <<= 1) {
            const unsigned o1 = (unsigned)__shfl_xor((int)a1, m, 64);
            const unsigned o2 = (unsigned)__shfl_xor((int)a2, m, 64);
            a2 = umin2(umin2(a2, o2), umed3(a1, a2, o1));
            a1 = umin2(a1, o1);
          }
          if (l15 == 0) {
            const int rl = wrow + mf * 16 + quad * 4 + i;   // C/D row (0..127)
            uint2 r; r.x = a1; r.y = a2;
            srec[(size_t)(mbase + rl) * NREC + g] = r;
          }
        }
    }

    #pragma unroll
    for (int j = 0; j < 4; ++j) cq_cur[j] = cq_nxt[j];
  }
}

// ---------------- finalize: exact fp32 dots for margin candidates ----------------
__global__ void vq_finalize(const float* __restrict__ x, const float* __restrict__ cb,
                            const float* __restrict__ xsq, const float* __restrict__ cbsq,
                            const uint2* __restrict__ srec,
                            float* __restrict__ outIdx, float* __restrict__ outDist,
                            float* __restrict__ codes) {
  const int wave = threadIdx.x >> 6, lane = threadIdx.x & 63;
  const int row = blockIdx.x * 4 + wave;    // one wave per row
  uint2 rec;
  if (lane < NREC) rec = srec[(size_t)row * NREC + lane];
  else { rec.x = 0x7fffffffu; rec.y = 0x7fffffffu; }
  const float v1 = (float)(rec.x >> 13) * 0.0625f - 2048.0f;
  const float v2 = (float)(rec.y >> 13) * 0.0625f - 2048.0f;
  const int c1 = (int)(rec.x & 8191u);
  const int c2 = (int)(rec.y & 8191u);

  float gm = v1;
  #pragma unroll
  for (int m = 1; m <= 32; m <<= 1) gm = fminf(gm, __shfl_xor(gm, m, 64));
  const float thr = gm + MARGIN;
  unsigned long long mask1 = __ballot(v1 <= thr);
  unsigned long long mask2 = __ballot(v2 <= thr);

  const float4 xv = *(const float4*)(x + (size_t)row * CDIM + lane * 4);
  const float xq = xsq[row];
  float best = __builtin_inff(); int bidx = 1 << 30;

  #pragma unroll
  for (int pass = 0; pass < 2; ++pass) {
    unsigned long long m = pass ? mask2 : mask1;
    const int fi = pass ? c2 : c1;
    while (m) {
      const int g = __builtin_ctzll((long long)m); m &= m - 1;
      const int ci = __shfl(fi, g, 64);
      const float4 cv = *(const float4*)(cb + (size_t)ci * CDIM + lane * 4);
      float s = xv.x * cv.x + xv.y * cv.y + xv.z * cv.z + xv.w * cv.w;
      #pragma unroll
      for (int mm = 1; mm <= 32; mm <<= 1) s += __shfl_xor(s, mm, 64);
      const float dist = xq + cbsq[ci] - 2.0f * s;
      if (dist < best || (dist == best && ci < bidx)) { best = dist; bidx = ci; }
    }
  }

  if (lane == 0) { outIdx[row] = (float)bidx; outDist[row] = best; }
  const float4 cw = *(const float4*)(cb + (size_t)bidx * CDIM + lane * 4);
  *(float4*)(codes + (size_t)row * CDIM + lane * 4) = cw;
}

extern "C" void kernel_launch(void* const* d_in, const int* in_sizes, int n_in,
                              void* d_out, int out_size, void* d_ws, size_t ws_size,
                              hipStream_t stream) {
  const float* x  = (const float*)d_in[0];   // [8,4096,256] fp32
  const float* cb = (const float*)d_in[1];   // [8192,256] fp32
  float* out = (float*)d_out;                // codes | idx | dist

  char* w = (char*)d_ws;                     // ~29.2 MB
  _Float16* xhi  = (_Float16*)(w);                 // 16 MB
  _Float16* cbhi = (_Float16*)(w + 16777216);      //  4 MB
  float*    xsq  = (float*)   (w + 20971520);      // 128 KB
  float*    cbsq = (float*)   (w + 21102592);      //  32 KB
  uint2*    srec = (uint2*)   (w + 21135360);      //  8 MB (32768*32*8B)

  vq_prep<<<(M_ROWS + KCODES) / 4, 256, 0, stream>>>(x, cb, xhi, cbhi, xsq, cbsq);
  const size_t smem = 65536;  // A only
  vq_pass1<<<dim3(M_ROWS / BM), 512, smem, stream>>>(xhi, cbhi, cbsq, srec);
  vq_finalize<<<M_ROWS / 4, 256, 0, stream>>>(x, cb, xsq, cbsq, srec,
                                              out + 8388608, out + 8421376, out);
}